// Round 9
// baseline (580.869 us; speedup 1.0000x reference)
//
#include <hip/hip_runtime.h>

// ---------------------------------------------------------------------------
// AttentionMultiHead: x[8,1024,1024] f32, per-head Wq/Wk/Wv[16,1024,64]+bias,
// Wo[1024,64]+bo. Outputs: z_out[8,1024,64] f32, att[8,16,1024,1024] f32 (raw).
//
// Attribution ledger (R6-R8): gemm_qkv ~50-75us, packs ~40us, out ~8us,
// attn ~250-270us vs ~95us traffic floor. Falsified attn theories: issue-mix
// (R6, invariant), store granularity (R8, -6). nt-stores real (-58, R7).
// R9 = PROBE ROUND: attn runs its kt loop TWICE (rep loop, oacc/lsum
// accumulate across reps -> heads = 2x/2x identical; att rewritten with same
// values). Purpose: (a) R9-R8 = direct attn time; (b) the ~2x dispatch
// (>400us) surfaces in the top-5 counter table -> first real counter row
// (WRITE/FETCH/VALUBusy/Occupancy) for attn. One variable; rest identical.
// ---------------------------------------------------------------------------

typedef __bf16 bf16x8 __attribute__((ext_vector_type(8)));
typedef float f32x4 __attribute__((ext_vector_type(4)));
typedef unsigned short u16x8 __attribute__((ext_vector_type(8)));
typedef unsigned short u16x4 __attribute__((ext_vector_type(4)));

typedef __attribute__((address_space(1))) unsigned int as1_u32;
typedef __attribute__((address_space(3))) unsigned int as3_u32;

#define MFMA16(a, b, c) __builtin_amdgcn_mfma_f32_16x16x32_bf16(a, b, c, 0, 0, 0)

__device__ __forceinline__ void gload_lds16(const void* g, void* l) {
  __builtin_amdgcn_global_load_lds((const as1_u32*)g, (as3_u32*)l, 16, 0, 0);
}

__device__ __forceinline__ unsigned short f2bf(float f) {
  union { float f; unsigned u; } a; a.f = f;
  unsigned r = a.u + 0x7FFFu + ((a.u >> 16) & 1u);  // RNE
  return (unsigned short)(r >> 16);
}

// ---------------- pack kernels ----------------
__global__ __launch_bounds__(256) void pack_x(const float* __restrict__ x, ushort* __restrict__ xb) {
  const size_t i = ((size_t)blockIdx.x * 256 + threadIdx.x) * 4;
  const float4 v = *(const float4*)(x + i);
  u16x4 o; o[0] = f2bf(v.x); o[1] = f2bf(v.y); o[2] = f2bf(v.z); o[3] = f2bf(v.w);
  *(u16x4*)(xb + i) = o;
}

// Wp[n][d], n = proj*1024 + h*64 + k  (B^T layout). XCD swizzle: 12288 blocks,
// chunk 1536/XCD so strided W reads stay in one XCD's L2.
__global__ __launch_bounds__(256) void pack_w(const float* __restrict__ Wq, const float* __restrict__ Wk,
                                              const float* __restrict__ Wv, ushort* __restrict__ Wp) {
  const int bid = blockIdx.x;
  const int swz = (bid & 7) * 1536 + (bid >> 3);
  const int o = swz * 256 + threadIdx.x;  // 0 .. 3072*1024
  const int n = o >> 10, d = o & 1023;
  const int proj = n >> 10, hk = n & 1023;
  const float* W = proj == 0 ? Wq : (proj == 1 ? Wk : Wv);
  const int h = hk >> 6, kk = hk & 63;
  Wp[o] = f2bf(W[((size_t)h * 1024 + d) * 64 + kk]);
}

__global__ __launch_bounds__(256) void pack_misc(const float* __restrict__ Wo, const float* __restrict__ bq,
                                                 const float* __restrict__ bk, const float* __restrict__ bv,
                                                 ushort* __restrict__ Wop, float* __restrict__ bqkv) {
  const int idx = blockIdx.x * 256 + threadIdx.x;
  if (idx < 65536) {
    const int n = idx >> 10, c = idx & 1023;   // Wop[n][c] = Wo[c][n]
    Wop[idx] = f2bf(Wo[c * 64 + n]);
  } else if (idx < 65536 + 3072) {
    const int n = idx - 65536;
    const int proj = n >> 10;
    const float* bb = proj == 0 ? bq : (proj == 1 ? bk : bv);
    bqkv[n] = bb[n & 1023];
  }
}

// ---------------- QKV projection GEMM (R3 structure) ----------------
__global__ __launch_bounds__(256) void gemm_qkv(const ushort* __restrict__ xb, const ushort* __restrict__ Wp,
                                                const float* __restrict__ bqkv, ushort* __restrict__ qo,
                                                ushort* __restrict__ ko, ushort* __restrict__ vTo) {
  __shared__ ushort As[128 * 32], Bs[128 * 32];
  const int bid = blockIdx.x;                 // 1536 blocks
  const int swz = (bid & 7) * 192 + (bid >> 3);
  const int by = swz / 24, bx = swz - by * 24;
  const int t = threadIdx.x, w = t >> 6, l = t & 63, lg = l >> 4, lr = l & 15;
  const int m0 = by * 128, n0 = bx * 128;
  const int wm = w >> 1, wn = w & 1;
  const int srow = l >> 2, sslot = l & 3;
  f32x4 acc[4][4] = {};
  for (int kt = 0; kt < 32; ++kt) {
    __syncthreads();
#pragma unroll
    for (int c = 0; c < 2; ++c) {
      const int cc = w * 2 + c;              // 0..7, 1KB chunk per wave-call
      const int row = cc * 16 + srow;        // LDS linear == row*64B + slot*16B
      gload_lds16(xb + (size_t)(m0 + row) * 1024 + kt * 32 + sslot * 8, &As[cc * 512]);
      gload_lds16(Wp + (size_t)(n0 + row) * 1024 + kt * 32 + sslot * 8, &Bs[cc * 512]);
    }
    __syncthreads();
    bf16x8 af[4], bfr[4];
#pragma unroll
    for (int mt = 0; mt < 4; ++mt)
      af[mt] = *(const bf16x8*)(&As[(wm * 64 + mt * 16 + lr) * 32 + lg * 8]);
#pragma unroll
    for (int nt = 0; nt < 4; ++nt)
      bfr[nt] = *(const bf16x8*)(&Bs[(wn * 64 + nt * 16 + lr) * 32 + lg * 8]);
#pragma unroll
    for (int mt = 0; mt < 4; ++mt)
#pragma unroll
      for (int nt = 0; nt < 4; ++nt)
        acc[mt][nt] = MFMA16(af[mt], bfr[nt], acc[mt][nt]);
  }
  // epilogue: bias + relu -> bf16. proj uniform across the wave (16-aligned n-chunks).
#pragma unroll
  for (int nt = 0; nt < 4; ++nt) {
    const int n = n0 + wn * 64 + nt * 16 + lr;
    const float bias = bqkv[n];
    const int proj = n >> 10, h = (n >> 6) & 15, dk = n & 63;
#pragma unroll
    for (int mt = 0; mt < 4; ++mt) {
      const int mb = m0 + wm * 64 + mt * 16 + lg * 4;  // j-quad base, same b & 4-aligned s
      const int b = mb >> 10, s = mb & 1023;
      float vv[4];
#pragma unroll
      for (int j = 0; j < 4; ++j) {
        float a = acc[mt][nt][j] + bias;
        vv[j] = a > 0.f ? a : 0.f;
      }
      if (proj == 2) {
        u16x4 o; o[0] = f2bf(vv[0]); o[1] = f2bf(vv[1]); o[2] = f2bf(vv[2]); o[3] = f2bf(vv[3]);
        *(u16x4*)(vTo + ((size_t)(b * 16 + h) * 64 + dk) * 1024 + s) = o;
      } else {
        ushort* op = proj == 0 ? qo : ko;
#pragma unroll
        for (int j = 0; j < 4; ++j)
          op[((size_t)(b * 16 + h) * 1024 + s + j) * 64 + dk] = f2bf(vv[j]);
      }
    }
  }
}

// ---------------- fused attention (PROBE: kt loop x2, identical output) ------
// oacc/lsum accumulate across both reps: heads = (2*oacc)/(2*lsum) is
// bit-identical to single-rep; att rows rewritten with identical values.
__global__ __launch_bounds__(256) void attn_kernel(const ushort* __restrict__ qg, const ushort* __restrict__ kg,
                                                   const ushort* __restrict__ vT, float* __restrict__ att,
                                                   ushort* __restrict__ heads) {
  const int bid = blockIdx.x;                 // 2048
  const int swz = (bid & 7) * 256 + (bid >> 3);
  const int qt = swz & 15, bh = swz >> 4;
  const int t = threadIdx.x, w = t >> 6, l = t & 63;
  const int lg = l >> 4, lr = l & 15;
  __shared__ ushort p_lds[4][16][80];     // 10 KB
  __shared__ float s_lds[4][16][136];     // 34 KB; [wave][qrow][2-kt cols + pad8]

  const ushort* qb = qg + (size_t)bh * 65536;
  const ushort* kb = kg + (size_t)bh * 65536;
  const ushort* vb = vT + (size_t)bh * 65536;
  const int qrow0 = qt * 64 + w * 16;

  const bf16x8 qf0 = *(const bf16x8*)(qb + (qrow0 + lr) * 64 + lg * 8);
  const bf16x8 qf1 = *(const bf16x8*)(qb + (qrow0 + lr) * 64 + 32 + lg * 8);

  const float C2 = 0.125f * 1.44269504f;  // 1/sqrt(64) in exp2 domain
  f32x4 oacc[4] = {};
  float lsum = 0.f;
  float* attw = att + ((size_t)bh * 1024 + qrow0) * 1024;
  const int fr = l >> 5, fc = (l & 31) * 4;   // flush: 2 rows/instr, 512B/row

  for (int rep = 0; rep < 2; ++rep) {         // PROBE: 2x work, same output
    for (int kt = 0; kt < 16; ++kt) {
      const int kv0 = kt * 64;
      f32x4 sf[4] = {};
#pragma unroll
      for (int nt = 0; nt < 4; ++nt) {
        const ushort* kr = kb + (kv0 + nt * 16 + lr) * 64 + lg * 8;
        bf16x8 kf0 = *(const bf16x8*)(kr);
        bf16x8 kf1 = *(const bf16x8*)(kr + 32);
        sf[nt] = MFMA16(kf0, qf0, sf[nt]);   // SWAPPED: A=K rows, B=Q rows
        sf[nt] = MFMA16(kf1, qf1, sf[nt]);   // => D[row=kv=lg*4+j][col=q=lr]
      }
      // prefetch V fragments (hide under LDS stage + exp VALU)
      bf16x8 vf[4][2];
#pragma unroll
      for (int nt = 0; nt < 4; ++nt) {
        const ushort* vr = vb + (nt * 16 + lr) * 1024 + kv0 + lg * 8;
        vf[nt][0] = *(const bf16x8*)(vr);
        vf[nt][1] = *(const bf16x8*)(vr + 32);
      }
      // stage raw scores to per-wave LDS (col half = kt parity)
      const int ch = (kt & 1) * 64;
#pragma unroll
      for (int nt = 0; nt < 4; ++nt)
        *(f32x4*)(&s_lds[w][lr][ch + nt * 16 + lg * 4]) = sf[nt];
      // p = exp2(s*C2) (no max subtraction), pack 4 kv -> one ds_write_b64
#pragma unroll
      for (int nt = 0; nt < 4; ++nt) {
        u16x4 pk;
#pragma unroll
        for (int j = 0; j < 4; ++j) {
          const float p = exp2f(sf[nt][j] * C2);
          lsum += p;
          pk[j] = f2bf(p);
        }
        *(u16x4*)(&p_lds[w][lr][nt * 16 + lg * 4]) = pk;
      }
      // per-wave LDS region; DS ops are wave-program-order; wait for writes
      asm volatile("s_waitcnt lgkmcnt(0)" ::: "memory");
      __builtin_amdgcn_sched_barrier(0);
      const bf16x8 pa0 = *(const bf16x8*)(&p_lds[w][lr][lg * 8]);
      const bf16x8 pa1 = *(const bf16x8*)(&p_lds[w][lr][32 + lg * 8]);
#pragma unroll
      for (int nt = 0; nt < 4; ++nt) {
        oacc[nt] = MFMA16(pa0, vf[nt][0], oacc[nt]);
        oacc[nt] = MFMA16(pa1, vf[nt][1], oacc[nt]);
      }
      // flush the 2-kt score group: contiguous 512B per row, 2 rows per instr
      if (kt & 1) {
        const int base = (kt - 1) * 64;
#pragma unroll
        for (int rr = 0; rr < 8; ++rr) {
          const int row = rr * 2 + fr;
          const f32x4 vv = *(const f32x4*)(&s_lds[w][row][fc]);
          __builtin_nontemporal_store(vv, (f32x4*)(attw + (size_t)row * 1024 + base + fc));
        }
      }
    }
  }
  // row sums: lane lr's partial over its lg-slice -> reduce across lg groups
  lsum += __shfl_xor(lsum, 16, 64);
  lsum += __shfl_xor(lsum, 32, 64);
  // oacc rows are q = lg*4+j -> fetch that row's sum (uniform over lg groups)
  float rdiv[4];
#pragma unroll
  for (int j = 0; j < 4; ++j) rdiv[j] = 1.f / __shfl(lsum, lg * 4 + j, 16);
  const int b = bh >> 4, h = bh & 15;
#pragma unroll
  for (int nt = 0; nt < 4; ++nt)
#pragma unroll
    for (int j = 0; j < 4; ++j)
      __builtin_nontemporal_store(f2bf(oacc[nt][j] * rdiv[j]),
          heads + (size_t)(b * 1024 + qrow0 + lg * 4 + j) * 1024 + h * 64 + nt * 16 + lr);
}

// ---------------- output GEMM: z_out = relu(heads @ Wo + bo) ----------------
__global__ __launch_bounds__(256) void gemm_out(const ushort* __restrict__ z, const ushort* __restrict__ Wop,
                                                const float* __restrict__ bo, float* __restrict__ out) {
  __shared__ float red[2][16][64];
  const int t = threadIdx.x, w = t >> 6, l = t & 63, lg = l >> 4, lr = l & 15;
  const int wm = w & 1, kh = w >> 1;
  const int m0 = blockIdx.x * 32 + wm * 16;
  f32x4 acc[4] = {};
  for (int kk = kh * 16; kk < kh * 16 + 16; ++kk) {
    bf16x8 af = *(const bf16x8*)(z + (size_t)(m0 + lr) * 1024 + kk * 32 + lg * 8);
#pragma unroll
    for (int nt = 0; nt < 4; ++nt) {
      bf16x8 bfr = *(const bf16x8*)(Wop + (size_t)(nt * 16 + lr) * 1024 + kk * 32 + lg * 8);
      acc[nt] = MFMA16(af, bfr, acc[nt]);
    }
  }
  if (kh == 1) {
#pragma unroll
    for (int nt = 0; nt < 4; ++nt)
#pragma unroll
      for (int j = 0; j < 4; ++j) red[wm][lg * 4 + j][nt * 16 + lr] = acc[nt][j];
  }
  __syncthreads();
  if (kh == 0) {
#pragma unroll
    for (int nt = 0; nt < 4; ++nt) {
      const int n = nt * 16 + lr;
      const float bb = bo[n];
#pragma unroll
      for (int j = 0; j < 4; ++j) {
        const int m = m0 + lg * 4 + j;
        float vv = acc[nt][j] + red[wm][lg * 4 + j][n] + bb;
        out[(size_t)m * 64 + n] = vv > 0.f ? vv : 0.f;
      }
    }
  }
}

// ---------------------------------------------------------------------------
extern "C" void kernel_launch(void* const* d_in, const int* in_sizes, int n_in,
                              void* d_out, int out_size, void* d_ws, size_t ws_size,
                              hipStream_t stream) {
  const float* x  = (const float*)d_in[0];
  const float* Wq = (const float*)d_in[1];
  const float* bq = (const float*)d_in[2];
  const float* Wk = (const float*)d_in[3];
  const float* bk = (const float*)d_in[4];
  const float* Wv = (const float*)d_in[5];
  const float* bv = (const float*)d_in[6];
  const float* Wo = (const float*)d_in[7];
  const float* bo = (const float*)d_in[8];
  float* out = (float*)d_out;            // z_out: 8*1024*64 = 524288 f32
  float* att = out + 524288;             // att:   8*16*1024*1024 f32

  // workspace layout (~92 MB)
  char* ws = (char*)d_ws;
  size_t off = 0;
  ushort* xb  = (ushort*)(ws + off); off += (size_t)8192 * 1024 * 2;
  ushort* Wp  = (ushort*)(ws + off); off += (size_t)3072 * 1024 * 2;
  ushort* Wop = (ushort*)(ws + off); off += (size_t)64 * 1024 * 2;
  float* bqkv = (float*)(ws + off);  off += (size_t)3072 * 4;
  ushort* q   = (ushort*)(ws + off); off += (size_t)128 * 1024 * 64 * 2;
  ushort* k   = (ushort*)(ws + off); off += (size_t)128 * 1024 * 64 * 2;
  ushort* vT  = (ushort*)(ws + off); off += (size_t)128 * 64 * 1024 * 2;
  ushort* hds = (ushort*)(ws + off); off += (size_t)8192 * 1024 * 2;
  (void)ws_size; (void)in_sizes; (void)n_in; (void)out_size;

  pack_x<<<dim3(8192), dim3(256), 0, stream>>>(x, xb);
  pack_w<<<dim3(12288), dim3(256), 0, stream>>>(Wq, Wk, Wv, Wp);
  pack_misc<<<dim3(269), dim3(256), 0, stream>>>(Wo, bq, bk, bv, Wop, bqkv);
  gemm_qkv<<<dim3(1536), dim3(256), 0, stream>>>(xb, Wp, bqkv, q, k, vT);
  attn_kernel<<<dim3(2048), dim3(256), 0, stream>>>(q, k, vT, att, hds);
  gemm_out<<<dim3(256), dim3(256), 0, stream>>>(hds, Wop, bo, out);
}

// Round 10
// 348.751 us; speedup vs baseline: 1.6656x; 1.6656x over previous
//
#include <hip/hip_runtime.h>

// ---------------------------------------------------------------------------
// AttentionMultiHead: x[8,1024,1024] f32, per-head Wq/Wk/Wv[16,1024,64]+bias,
// Wo[1024,64]+bo. Outputs: z_out[8,1024,64] f32, att[8,16,1024,1024] f32 (raw).
//
// Attribution ledger (R9 probe, direct): attn = 233us (2x-rep dispatch 509us:
// FETCH 25MB -> reads cached; 27% HBM; MfmaUtil 5.5%; VALUBusy 24%; Occ 33%).
// => latency-serialized, not BW/pipe-bound. Mechanism: vmcnt is IN-ORDER and
// counts stores; loads for kt are issued after att-stores of kt-1, so every
// MFMA load-wait drains the just-issued HBM nt-stores (~1e3 cy each iter).
// R10 fix: software-pipeline att stores one iteration late (sprev regs);
// per iter: issue loads FIRST, sched_barrier, then store kt-1. Load waits
// become vmcnt(16) (loads oldest) -> stores retire in the shadow.
// Also dropped R8's s_lds staging (parity ~0): LDS 44->10KB.
// ---------------------------------------------------------------------------

typedef __bf16 bf16x8 __attribute__((ext_vector_type(8)));
typedef float f32x4 __attribute__((ext_vector_type(4)));
typedef unsigned short u16x8 __attribute__((ext_vector_type(8)));
typedef unsigned short u16x4 __attribute__((ext_vector_type(4)));

typedef __attribute__((address_space(1))) unsigned int as1_u32;
typedef __attribute__((address_space(3))) unsigned int as3_u32;

#define MFMA16(a, b, c) __builtin_amdgcn_mfma_f32_16x16x32_bf16(a, b, c, 0, 0, 0)

__device__ __forceinline__ void gload_lds16(const void* g, void* l) {
  __builtin_amdgcn_global_load_lds((const as1_u32*)g, (as3_u32*)l, 16, 0, 0);
}

__device__ __forceinline__ unsigned short f2bf(float f) {
  union { float f; unsigned u; } a; a.f = f;
  unsigned r = a.u + 0x7FFFu + ((a.u >> 16) & 1u);  // RNE
  return (unsigned short)(r >> 16);
}

// ---------------- pack kernels ----------------
__global__ __launch_bounds__(256) void pack_x(const float* __restrict__ x, ushort* __restrict__ xb) {
  const size_t i = ((size_t)blockIdx.x * 256 + threadIdx.x) * 4;
  const float4 v = *(const float4*)(x + i);
  u16x4 o; o[0] = f2bf(v.x); o[1] = f2bf(v.y); o[2] = f2bf(v.z); o[3] = f2bf(v.w);
  *(u16x4*)(xb + i) = o;
}

// Wp[n][d], n = proj*1024 + h*64 + k  (B^T layout). XCD swizzle: 12288 blocks,
// chunk 1536/XCD so strided W reads stay in one XCD's L2.
__global__ __launch_bounds__(256) void pack_w(const float* __restrict__ Wq, const float* __restrict__ Wk,
                                              const float* __restrict__ Wv, ushort* __restrict__ Wp) {
  const int bid = blockIdx.x;
  const int swz = (bid & 7) * 1536 + (bid >> 3);
  const int o = swz * 256 + threadIdx.x;  // 0 .. 3072*1024
  const int n = o >> 10, d = o & 1023;
  const int proj = n >> 10, hk = n & 1023;
  const float* W = proj == 0 ? Wq : (proj == 1 ? Wk : Wv);
  const int h = hk >> 6, kk = hk & 63;
  Wp[o] = f2bf(W[((size_t)h * 1024 + d) * 64 + kk]);
}

__global__ __launch_bounds__(256) void pack_misc(const float* __restrict__ Wo, const float* __restrict__ bq,
                                                 const float* __restrict__ bk, const float* __restrict__ bv,
                                                 ushort* __restrict__ Wop, float* __restrict__ bqkv) {
  const int idx = blockIdx.x * 256 + threadIdx.x;
  if (idx < 65536) {
    const int n = idx >> 10, c = idx & 1023;   // Wop[n][c] = Wo[c][n]
    Wop[idx] = f2bf(Wo[c * 64 + n]);
  } else if (idx < 65536 + 3072) {
    const int n = idx - 65536;
    const int proj = n >> 10;
    const float* bb = proj == 0 ? bq : (proj == 1 ? bk : bv);
    bqkv[n] = bb[n & 1023];
  }
}

// ---------------- QKV projection GEMM (R3 structure) ----------------
__global__ __launch_bounds__(256) void gemm_qkv(const ushort* __restrict__ xb, const ushort* __restrict__ Wp,
                                                const float* __restrict__ bqkv, ushort* __restrict__ qo,
                                                ushort* __restrict__ ko, ushort* __restrict__ vTo) {
  __shared__ ushort As[128 * 32], Bs[128 * 32];
  const int bid = blockIdx.x;                 // 1536 blocks
  const int swz = (bid & 7) * 192 + (bid >> 3);
  const int by = swz / 24, bx = swz - by * 24;
  const int t = threadIdx.x, w = t >> 6, l = t & 63, lg = l >> 4, lr = l & 15;
  const int m0 = by * 128, n0 = bx * 128;
  const int wm = w >> 1, wn = w & 1;
  const int srow = l >> 2, sslot = l & 3;
  f32x4 acc[4][4] = {};
  for (int kt = 0; kt < 32; ++kt) {
    __syncthreads();
#pragma unroll
    for (int c = 0; c < 2; ++c) {
      const int cc = w * 2 + c;              // 0..7, 1KB chunk per wave-call
      const int row = cc * 16 + srow;        // LDS linear == row*64B + slot*16B
      gload_lds16(xb + (size_t)(m0 + row) * 1024 + kt * 32 + sslot * 8, &As[cc * 512]);
      gload_lds16(Wp + (size_t)(n0 + row) * 1024 + kt * 32 + sslot * 8, &Bs[cc * 512]);
    }
    __syncthreads();
    bf16x8 af[4], bfr[4];
#pragma unroll
    for (int mt = 0; mt < 4; ++mt)
      af[mt] = *(const bf16x8*)(&As[(wm * 64 + mt * 16 + lr) * 32 + lg * 8]);
#pragma unroll
    for (int nt = 0; nt < 4; ++nt)
      bfr[nt] = *(const bf16x8*)(&Bs[(wn * 64 + nt * 16 + lr) * 32 + lg * 8]);
#pragma unroll
    for (int mt = 0; mt < 4; ++mt)
#pragma unroll
      for (int nt = 0; nt < 4; ++nt)
        acc[mt][nt] = MFMA16(af[mt], bfr[nt], acc[mt][nt]);
  }
  // epilogue: bias + relu -> bf16. proj uniform across the wave (16-aligned n-chunks).
#pragma unroll
  for (int nt = 0; nt < 4; ++nt) {
    const int n = n0 + wn * 64 + nt * 16 + lr;
    const float bias = bqkv[n];
    const int proj = n >> 10, h = (n >> 6) & 15, dk = n & 63;
#pragma unroll
    for (int mt = 0; mt < 4; ++mt) {
      const int mb = m0 + wm * 64 + mt * 16 + lg * 4;  // j-quad base, same b & 4-aligned s
      const int b = mb >> 10, s = mb & 1023;
      float vv[4];
#pragma unroll
      for (int j = 0; j < 4; ++j) {
        float a = acc[mt][nt][j] + bias;
        vv[j] = a > 0.f ? a : 0.f;
      }
      if (proj == 2) {
        u16x4 o; o[0] = f2bf(vv[0]); o[1] = f2bf(vv[1]); o[2] = f2bf(vv[2]); o[3] = f2bf(vv[3]);
        *(u16x4*)(vTo + ((size_t)(b * 16 + h) * 64 + dk) * 1024 + s) = o;
      } else {
        ushort* op = proj == 0 ? qo : ko;
#pragma unroll
        for (int j = 0; j < 4; ++j)
          op[((size_t)(b * 16 + h) * 1024 + s + j) * 64 + dk] = f2bf(vv[j]);
      }
    }
  }
}

// ---------------- fused attention (store-delayed pipeline) ----------------
// 2048 blocks (XCD-swizzled); 4 waves x 16 q-rows (lane lr = q-row).
// mfma(K,Q) => lane holds S[q=lr][kv]. Per kt: issue K,V loads FIRST,
// sched_barrier, then nt-store the PREVIOUS kt's scores from sprev regs.
// In-order vmcnt => load waits are vmcnt(16) and never drain the stores;
// stores retire under the following MFMA/VALU phase. Softmax no-max
// (bounded scores); P via ds_write_b64 round-trip; heads bf16 nt.
__global__ __launch_bounds__(256) void attn_kernel(const ushort* __restrict__ qg, const ushort* __restrict__ kg,
                                                   const ushort* __restrict__ vT, float* __restrict__ att,
                                                   ushort* __restrict__ heads) {
  const int bid = blockIdx.x;                 // 2048
  const int swz = (bid & 7) * 256 + (bid >> 3);
  const int qt = swz & 15, bh = swz >> 4;
  const int t = threadIdx.x, w = t >> 6, l = t & 63;
  const int lg = l >> 4, lr = l & 15;
  __shared__ ushort p_lds[4][16][80];     // 10 KB, single buffer (per-wave DS order)

  const ushort* qb = qg + (size_t)bh * 65536;
  const ushort* kb = kg + (size_t)bh * 65536;
  const ushort* vb = vT + (size_t)bh * 65536;
  const int qrow0 = qt * 64 + w * 16;

  const bf16x8 qf0 = *(const bf16x8*)(qb + (qrow0 + lr) * 64 + lg * 8);
  const bf16x8 qf1 = *(const bf16x8*)(qb + (qrow0 + lr) * 64 + 32 + lg * 8);

  const float C2 = 0.125f * 1.44269504f;  // 1/sqrt(64) in exp2 domain
  f32x4 oacc[4] = {};
  float lsum = 0.f;
  float* attw = att + ((size_t)bh * 1024 + qrow0) * 1024;
  f32x4 sprev[4];

  for (int kt = 0; kt < 16; ++kt) {
    const int kv0 = kt * 64;
    // (1) issue ALL of this kt's loads first (oldest outstanding VMEM ops)
    bf16x8 kf0[4], kf1[4], vf0[4], vf1[4];
#pragma unroll
    for (int nt = 0; nt < 4; ++nt) {
      const ushort* kr = kb + (kv0 + nt * 16 + lr) * 64 + lg * 8;
      kf0[nt] = *(const bf16x8*)(kr);
      kf1[nt] = *(const bf16x8*)(kr + 32);
      const ushort* vr = vb + (nt * 16 + lr) * 1024 + kv0 + lg * 8;
      vf0[nt] = *(const bf16x8*)(vr);
      vf1[nt] = *(const bf16x8*)(vr + 32);
    }
    // pin: loads stay above, stores stay below this point
    __builtin_amdgcn_sched_barrier(0);
    // (2) nt-store PREVIOUS kt's raw scores (one-iteration-late pipeline)
    if (kt) {
#pragma unroll
      for (int nt = 0; nt < 4; ++nt)
        __builtin_nontemporal_store(sprev[nt],
            (f32x4*)(attw + (size_t)lr * 1024 + (kv0 - 64) + nt * 16 + lg * 4));
    }
    // (3) QK^T (swapped: A=K rows, B=Q rows => D[row=kv=lg*4+j][col=q=lr])
    f32x4 sf[4] = {};
#pragma unroll
    for (int nt = 0; nt < 4; ++nt) {
      sf[nt] = MFMA16(kf0[nt], qf0, sf[nt]);
      sf[nt] = MFMA16(kf1[nt], qf1, sf[nt]);
    }
    // (4) p = exp2(s*C2), per-lane sum, pack 4 kv -> one ds_write_b64
#pragma unroll
    for (int nt = 0; nt < 4; ++nt) {
      u16x4 pk;
#pragma unroll
      for (int j = 0; j < 4; ++j) {
        const float p = exp2f(sf[nt][j] * C2);
        lsum += p;
        pk[j] = f2bf(p);
      }
      *(u16x4*)(&p_lds[w][lr][nt * 16 + lg * 4]) = pk;
    }
    // per-wave LDS region; DS ops are wave-program-order; wait for writes
    asm volatile("s_waitcnt lgkmcnt(0)" ::: "memory");
    __builtin_amdgcn_sched_barrier(0);
    const bf16x8 pa0 = *(const bf16x8*)(&p_lds[w][lr][lg * 8]);
    const bf16x8 pa1 = *(const bf16x8*)(&p_lds[w][lr][32 + lg * 8]);
#pragma unroll
    for (int nt = 0; nt < 4; ++nt) {
      oacc[nt] = MFMA16(pa0, vf0[nt], oacc[nt]);
      oacc[nt] = MFMA16(pa1, vf1[nt], oacc[nt]);
    }
    // (5) keep this kt's scores for next iteration's store slot
#pragma unroll
    for (int nt = 0; nt < 4; ++nt) sprev[nt] = sf[nt];
  }
  // pipeline drain: store kt=15 scores
#pragma unroll
  for (int nt = 0; nt < 4; ++nt)
    __builtin_nontemporal_store(sprev[nt],
        (f32x4*)(attw + (size_t)lr * 1024 + 960 + nt * 16 + lg * 4));
  // row sums: lane lr's partial over its lg-slice -> reduce across lg groups
  lsum += __shfl_xor(lsum, 16, 64);
  lsum += __shfl_xor(lsum, 32, 64);
  // oacc rows are q = lg*4+j -> fetch that row's sum (uniform over lg groups)
  float rdiv[4];
#pragma unroll
  for (int j = 0; j < 4; ++j) rdiv[j] = 1.f / __shfl(lsum, lg * 4 + j, 16);
  const int b = bh >> 4, h = bh & 15;
#pragma unroll
  for (int nt = 0; nt < 4; ++nt)
#pragma unroll
    for (int j = 0; j < 4; ++j)
      __builtin_nontemporal_store(f2bf(oacc[nt][j] * rdiv[j]),
          heads + (size_t)(b * 1024 + qrow0 + lg * 4 + j) * 1024 + h * 64 + nt * 16 + lr);
}

// ---------------- output GEMM: z_out = relu(heads @ Wo + bo) ----------------
__global__ __launch_bounds__(256) void gemm_out(const ushort* __restrict__ z, const ushort* __restrict__ Wop,
                                                const float* __restrict__ bo, float* __restrict__ out) {
  __shared__ float red[2][16][64];
  const int t = threadIdx.x, w = t >> 6, l = t & 63, lg = l >> 4, lr = l & 15;
  const int wm = w & 1, kh = w >> 1;
  const int m0 = blockIdx.x * 32 + wm * 16;
  f32x4 acc[4] = {};
  for (int kk = kh * 16; kk < kh * 16 + 16; ++kk) {
    bf16x8 af = *(const bf16x8*)(z + (size_t)(m0 + lr) * 1024 + kk * 32 + lg * 8);
#pragma unroll
    for (int nt = 0; nt < 4; ++nt) {
      bf16x8 bfr = *(const bf16x8*)(Wop + (size_t)(nt * 16 + lr) * 1024 + kk * 32 + lg * 8);
      acc[nt] = MFMA16(af, bfr, acc[nt]);
    }
  }
  if (kh == 1) {
#pragma unroll
    for (int nt = 0; nt < 4; ++nt)
#pragma unroll
      for (int j = 0; j < 4; ++j) red[wm][lg * 4 + j][nt * 16 + lr] = acc[nt][j];
  }
  __syncthreads();
  if (kh == 0) {
#pragma unroll
    for (int nt = 0; nt < 4; ++nt) {
      const int n = nt * 16 + lr;
      const float bb = bo[n];
#pragma unroll
      for (int j = 0; j < 4; ++j) {
        const int m = m0 + lg * 4 + j;
        float vv = acc[nt][j] + red[wm][lg * 4 + j][n] + bb;
        out[(size_t)m * 64 + n] = vv > 0.f ? vv : 0.f;
      }
    }
  }
}

// ---------------------------------------------------------------------------
extern "C" void kernel_launch(void* const* d_in, const int* in_sizes, int n_in,
                              void* d_out, int out_size, void* d_ws, size_t ws_size,
                              hipStream_t stream) {
  const float* x  = (const float*)d_in[0];
  const float* Wq = (const float*)d_in[1];
  const float* bq = (const float*)d_in[2];
  const float* Wk = (const float*)d_in[3];
  const float* bk = (const float*)d_in[4];
  const float* Wv = (const float*)d_in[5];
  const float* bv = (const float*)d_in[6];
  const float* Wo = (const float*)d_in[7];
  const float* bo = (const float*)d_in[8];
  float* out = (float*)d_out;            // z_out: 8*1024*64 = 524288 f32
  float* att = out + 524288;             // att:   8*16*1024*1024 f32

  // workspace layout (~92 MB)
  char* ws = (char*)d_ws;
  size_t off = 0;
  ushort* xb  = (ushort*)(ws + off); off += (size_t)8192 * 1024 * 2;
  ushort* Wp  = (ushort*)(ws + off); off += (size_t)3072 * 1024 * 2;
  ushort* Wop = (ushort*)(ws + off); off += (size_t)64 * 1024 * 2;
  float* bqkv = (float*)(ws + off);  off += (size_t)3072 * 4;
  ushort* q   = (ushort*)(ws + off); off += (size_t)128 * 1024 * 64 * 2;
  ushort* k   = (ushort*)(ws + off); off += (size_t)128 * 1024 * 64 * 2;
  ushort* vT  = (ushort*)(ws + off); off += (size_t)128 * 64 * 1024 * 2;
  ushort* hds = (ushort*)(ws + off); off += (size_t)8192 * 1024 * 2;
  (void)ws_size; (void)in_sizes; (void)n_in; (void)out_size;

  pack_x<<<dim3(8192), dim3(256), 0, stream>>>(x, xb);
  pack_w<<<dim3(12288), dim3(256), 0, stream>>>(Wq, Wk, Wv, Wp);
  pack_misc<<<dim3(269), dim3(256), 0, stream>>>(Wo, bq, bk, bv, Wop, bqkv);
  gemm_qkv<<<dim3(1536), dim3(256), 0, stream>>>(xb, Wp, bqkv, q, k, vT);
  attn_kernel<<<dim3(2048), dim3(256), 0, stream>>>(q, k, vT, att, hds);
  gemm_out<<<dim3(256), dim3(256), 0, stream>>>(hds, Wop, bo, out);
}

// Round 11
// 278.583 us; speedup vs baseline: 2.0851x; 1.2519x over previous
//
#include <hip/hip_runtime.h>

// ---------------------------------------------------------------------------
// AttentionMultiHead: x[8,1024,1024] f32, per-head Wq/Wk/Wv[16,1024,64]+bias,
// Wo[1024,64]+bo. Outputs: z_out[8,1024,64] f32, att[8,16,1024,1024] f32 (raw).
//
// Ledger: packs ~40us, gemm_qkv ~55us, out ~8us, attn ~233us (direct, R9).
// attn facts (R9 counters): WRITE 554MB/rep, FETCH 25MB (reads L2-cached),
// 2.17 TB/s, MfmaUtil 5.5%, VALUBusy 24%, Occ 33%. Falsified: issue-mix (R6),
// store granularity (R8), store-drain pipeline (R10). Surviving theory:
// VMEM REQUEST-RATE bound - every load/store is 16-way scattered (16 rows x
// 64B, 4KB stride) and all 4 waves redundantly load the same K/V tile
// => ~20K line-requests/block.
// R11: K/V tiles staged to LDS once per block via coalesced global_load_lds
// (1KB/call, chunk-XOR source pre-swizzle for conflict-free ds_read_b128);
// QK^T/PV operands move to the DS pipe. Requests/block ~20K -> ~6K.
// ---------------------------------------------------------------------------

typedef __bf16 bf16x8 __attribute__((ext_vector_type(8)));
typedef float f32x4 __attribute__((ext_vector_type(4)));
typedef unsigned short u16x8 __attribute__((ext_vector_type(8)));
typedef unsigned short u16x4 __attribute__((ext_vector_type(4)));

typedef __attribute__((address_space(1))) unsigned int as1_u32;
typedef __attribute__((address_space(3))) unsigned int as3_u32;

#define MFMA16(a, b, c) __builtin_amdgcn_mfma_f32_16x16x32_bf16(a, b, c, 0, 0, 0)

__device__ __forceinline__ void gload_lds16(const void* g, void* l) {
  __builtin_amdgcn_global_load_lds((const as1_u32*)g, (as3_u32*)l, 16, 0, 0);
}

__device__ __forceinline__ unsigned short f2bf(float f) {
  union { float f; unsigned u; } a; a.f = f;
  unsigned r = a.u + 0x7FFFu + ((a.u >> 16) & 1u);  // RNE
  return (unsigned short)(r >> 16);
}

// ---------------- pack kernels ----------------
__global__ __launch_bounds__(256) void pack_x(const float* __restrict__ x, ushort* __restrict__ xb) {
  const size_t i = ((size_t)blockIdx.x * 256 + threadIdx.x) * 4;
  const float4 v = *(const float4*)(x + i);
  u16x4 o; o[0] = f2bf(v.x); o[1] = f2bf(v.y); o[2] = f2bf(v.z); o[3] = f2bf(v.w);
  *(u16x4*)(xb + i) = o;
}

// Wp[n][d], n = proj*1024 + h*64 + k  (B^T layout). XCD swizzle: 12288 blocks,
// chunk 1536/XCD so strided W reads stay in one XCD's L2.
__global__ __launch_bounds__(256) void pack_w(const float* __restrict__ Wq, const float* __restrict__ Wk,
                                              const float* __restrict__ Wv, ushort* __restrict__ Wp) {
  const int bid = blockIdx.x;
  const int swz = (bid & 7) * 1536 + (bid >> 3);
  const int o = swz * 256 + threadIdx.x;  // 0 .. 3072*1024
  const int n = o >> 10, d = o & 1023;
  const int proj = n >> 10, hk = n & 1023;
  const float* W = proj == 0 ? Wq : (proj == 1 ? Wk : Wv);
  const int h = hk >> 6, kk = hk & 63;
  Wp[o] = f2bf(W[((size_t)h * 1024 + d) * 64 + kk]);
}

__global__ __launch_bounds__(256) void pack_misc(const float* __restrict__ Wo, const float* __restrict__ bq,
                                                 const float* __restrict__ bk, const float* __restrict__ bv,
                                                 ushort* __restrict__ Wop, float* __restrict__ bqkv) {
  const int idx = blockIdx.x * 256 + threadIdx.x;
  if (idx < 65536) {
    const int n = idx >> 10, c = idx & 1023;   // Wop[n][c] = Wo[c][n]
    Wop[idx] = f2bf(Wo[c * 64 + n]);
  } else if (idx < 65536 + 3072) {
    const int n = idx - 65536;
    const int proj = n >> 10;
    const float* bb = proj == 0 ? bq : (proj == 1 ? bk : bv);
    bqkv[n] = bb[n & 1023];
  }
}

// ---------------- QKV projection GEMM (R3 structure) ----------------
__global__ __launch_bounds__(256) void gemm_qkv(const ushort* __restrict__ xb, const ushort* __restrict__ Wp,
                                                const float* __restrict__ bqkv, ushort* __restrict__ qo,
                                                ushort* __restrict__ ko, ushort* __restrict__ vTo) {
  __shared__ ushort As[128 * 32], Bs[128 * 32];
  const int bid = blockIdx.x;                 // 1536 blocks
  const int swz = (bid & 7) * 192 + (bid >> 3);
  const int by = swz / 24, bx = swz - by * 24;
  const int t = threadIdx.x, w = t >> 6, l = t & 63, lg = l >> 4, lr = l & 15;
  const int m0 = by * 128, n0 = bx * 128;
  const int wm = w >> 1, wn = w & 1;
  const int srow = l >> 2, sslot = l & 3;
  f32x4 acc[4][4] = {};
  for (int kt = 0; kt < 32; ++kt) {
    __syncthreads();
#pragma unroll
    for (int c = 0; c < 2; ++c) {
      const int cc = w * 2 + c;              // 0..7, 1KB chunk per wave-call
      const int row = cc * 16 + srow;        // LDS linear == row*64B + slot*16B
      gload_lds16(xb + (size_t)(m0 + row) * 1024 + kt * 32 + sslot * 8, &As[cc * 512]);
      gload_lds16(Wp + (size_t)(n0 + row) * 1024 + kt * 32 + sslot * 8, &Bs[cc * 512]);
    }
    __syncthreads();
    bf16x8 af[4], bfr[4];
#pragma unroll
    for (int mt = 0; mt < 4; ++mt)
      af[mt] = *(const bf16x8*)(&As[(wm * 64 + mt * 16 + lr) * 32 + lg * 8]);
#pragma unroll
    for (int nt = 0; nt < 4; ++nt)
      bfr[nt] = *(const bf16x8*)(&Bs[(wn * 64 + nt * 16 + lr) * 32 + lg * 8]);
#pragma unroll
    for (int mt = 0; mt < 4; ++mt)
#pragma unroll
      for (int nt = 0; nt < 4; ++nt)
        acc[mt][nt] = MFMA16(af[mt], bfr[nt], acc[mt][nt]);
  }
  // epilogue: bias + relu -> bf16. proj uniform across the wave (16-aligned n-chunks).
#pragma unroll
  for (int nt = 0; nt < 4; ++nt) {
    const int n = n0 + wn * 64 + nt * 16 + lr;
    const float bias = bqkv[n];
    const int proj = n >> 10, h = (n >> 6) & 15, dk = n & 63;
#pragma unroll
    for (int mt = 0; mt < 4; ++mt) {
      const int mb = m0 + wm * 64 + mt * 16 + lg * 4;  // j-quad base, same b & 4-aligned s
      const int b = mb >> 10, s = mb & 1023;
      float vv[4];
#pragma unroll
      for (int j = 0; j < 4; ++j) {
        float a = acc[mt][nt][j] + bias;
        vv[j] = a > 0.f ? a : 0.f;
      }
      if (proj == 2) {
        u16x4 o; o[0] = f2bf(vv[0]); o[1] = f2bf(vv[1]); o[2] = f2bf(vv[2]); o[3] = f2bf(vv[3]);
        *(u16x4*)(vTo + ((size_t)(b * 16 + h) * 64 + dk) * 1024 + s) = o;
      } else {
        ushort* op = proj == 0 ? qo : ko;
#pragma unroll
        for (int j = 0; j < 4; ++j)
          op[((size_t)(b * 16 + h) * 1024 + s + j) * 64 + dk] = f2bf(vv[j]);
      }
    }
  }
}

// ---------------- fused attention (LDS-shared K/V, request-coalesced) --------
// 2048 blocks (XCD-swizzled); 4 waves x 16 q-rows (lane lr = q-row).
// Per 128-kv group: stage K tile (128x64 bf16, 16KB) + V tile (64x128 of vT,
// 16KB) into LDS via coalesced 1KB global_load_lds calls (8 calls/wave) with
// chunk-XOR source pre-swizzle; then QK^T (swapped), exp/pack->p_lds,
// direct nt att stores (issued mid-compute, LDS-only PV behind them), PV.
// All MFMA operands come from the DS pipe -> TA sees only coalesced staging
// + att stores.
__global__ __launch_bounds__(256) void attn_kernel(const ushort* __restrict__ qg, const ushort* __restrict__ kg,
                                                   const ushort* __restrict__ vT, float* __restrict__ att,
                                                   ushort* __restrict__ heads) {
  const int bid = blockIdx.x;                 // 2048
  const int swz = (bid & 7) * 256 + (bid >> 3);
  const int qt = swz & 15, bh = swz >> 4;
  const int t = threadIdx.x, w = t >> 6, l = t & 63;
  const int lg = l >> 4, lr = l & 15;
  __shared__ ushort Ks[128 * 64];         // 16 KB, chunk-swizzled rows of 128B
  __shared__ ushort Vs[64 * 128];         // 16 KB, chunk-swizzled rows of 256B
  __shared__ ushort p_lds[4][16][136];    // 17 KB

  const ushort* qb = qg + (size_t)bh * 65536;
  const ushort* kb = kg + (size_t)bh * 65536;
  const ushort* vb = vT + (size_t)bh * 65536;
  const int qrow0 = qt * 64 + w * 16;

  // Q fragments: lane lr = q-row (B-frag for swapped mfma)
  const bf16x8 qf0 = *(const bf16x8*)(qb + (qrow0 + lr) * 64 + lg * 8);
  const bf16x8 qf1 = *(const bf16x8*)(qb + (qrow0 + lr) * 64 + 32 + lg * 8);

  // staging lane geometry (per 1KB call)
  const int krow = l >> 3, kch = l & 7;    // K: 8 rows x 8 chunks(16B)
  const int vrow = l >> 4, vch = l & 15;   // V: 4 rows x 16 chunks(16B)

  const float C2 = 0.125f * 1.44269504f;   // 1/sqrt(64) in exp2 domain
  f32x4 oacc[4] = {};
  float lsum = 0.f;
  float* attw = att + ((size_t)bh * 1024 + qrow0) * 1024;

  for (int g = 0; g < 8; ++g) {
    const int kv0 = g * 128;
    __syncthreads();   // all waves done reading previous group's tiles
    // stage: each wave 4 K-calls + 4 V-calls, 1KB each, coalesced.
    // source chunk pre-swizzled (c ^ row) so linear LDS reads back swizzled.
#pragma unroll
    for (int c2 = 0; c2 < 4; ++c2) {
      const int call = w * 4 + c2;
      const int r = call * 8 + krow;       // K local row 0..127
      gload_lds16(kb + (size_t)(kv0 + r) * 64 + ((kch ^ (r & 7)) * 8), &Ks[call * 512]);
      const int rv = call * 4 + vrow;      // V local row (dk) 0..63
      gload_lds16(vb + (size_t)rv * 1024 + kv0 + ((vch ^ (rv & 15)) * 8), &Vs[call * 512]);
    }
    __syncthreads();   // stage complete (compiler drains vmcnt here)
    // QK^T from LDS (swapped: A=K rows, B=Q) => sf[f][j] = S[q=lr][kv=f*16+lg*4+j]
    f32x4 sf[8];
#pragma unroll
    for (int f = 0; f < 8; ++f) {
      const int r = f * 16 + lr;
      const bf16x8 kf0 = *(const bf16x8*)(&Ks[r * 64 + ((lg ^ (r & 7)) * 8)]);
      const bf16x8 kf1 = *(const bf16x8*)(&Ks[r * 64 + (((4 + lg) ^ (r & 7)) * 8)]);
      f32x4 s = {};
      s = MFMA16(kf0, qf0, s);
      s = MFMA16(kf1, qf1, s);
      sf[f] = s;
    }
    // exp/pack -> p_lds; raw scores -> att (nt, direct; PV phase covers retire)
#pragma unroll
    for (int f = 0; f < 8; ++f) {
      u16x4 pk;
#pragma unroll
      for (int j = 0; j < 4; ++j) {
        const float p = exp2f(sf[f][j] * C2);
        lsum += p;
        pk[j] = f2bf(p);
      }
      *(u16x4*)(&p_lds[w][lr][f * 16 + lg * 4]) = pk;
      __builtin_nontemporal_store(sf[f],
          (f32x4*)(attw + (size_t)lr * 1024 + kv0 + f * 16 + lg * 4));
    }
    // per-wave LDS region; DS ops wave-program-order; wait for P writes
    asm volatile("s_waitcnt lgkmcnt(0)" ::: "memory");
    __builtin_amdgcn_sched_barrier(0);
    // PV from LDS: oacc[nt] += P[128] x V[128][dk]
#pragma unroll
    for (int s = 0; s < 4; ++s) {
      const bf16x8 pa = *(const bf16x8*)(&p_lds[w][lr][s * 32 + lg * 8]);
#pragma unroll
      for (int nt = 0; nt < 4; ++nt) {
        const int r = nt * 16 + lr;
        const bf16x8 vf = *(const bf16x8*)(&Vs[r * 128 + (((s * 4 + lg) ^ lr) * 8)]);
        oacc[nt] = MFMA16(pa, vf, oacc[nt]);
      }
    }
  }
  // row sums: reduce lane partials across lg groups
  lsum += __shfl_xor(lsum, 16, 64);
  lsum += __shfl_xor(lsum, 32, 64);
  float rdiv[4];
#pragma unroll
  for (int j = 0; j < 4; ++j) rdiv[j] = 1.f / __shfl(lsum, lg * 4 + j, 16);
  const int b = bh >> 4, h = bh & 15;
#pragma unroll
  for (int nt = 0; nt < 4; ++nt)
#pragma unroll
    for (int j = 0; j < 4; ++j)
      __builtin_nontemporal_store(f2bf(oacc[nt][j] * rdiv[j]),
          heads + (size_t)(b * 1024 + qrow0 + lg * 4 + j) * 1024 + h * 64 + nt * 16 + lr);
}

// ---------------- output GEMM: z_out = relu(heads @ Wo + bo) ----------------
__global__ __launch_bounds__(256) void gemm_out(const ushort* __restrict__ z, const ushort* __restrict__ Wop,
                                                const float* __restrict__ bo, float* __restrict__ out) {
  __shared__ float red[2][16][64];
  const int t = threadIdx.x, w = t >> 6, l = t & 63, lg = l >> 4, lr = l & 15;
  const int wm = w & 1, kh = w >> 1;
  const int m0 = blockIdx.x * 32 + wm * 16;
  f32x4 acc[4] = {};
  for (int kk = kh * 16; kk < kh * 16 + 16; ++kk) {
    bf16x8 af = *(const bf16x8*)(z + (size_t)(m0 + lr) * 1024 + kk * 32 + lg * 8);
#pragma unroll
    for (int nt = 0; nt < 4; ++nt) {
      bf16x8 bfr = *(const bf16x8*)(Wop + (size_t)(nt * 16 + lr) * 1024 + kk * 32 + lg * 8);
      acc[nt] = MFMA16(af, bfr, acc[nt]);
    }
  }
  if (kh == 1) {
#pragma unroll
    for (int nt = 0; nt < 4; ++nt)
#pragma unroll
      for (int j = 0; j < 4; ++j) red[wm][lg * 4 + j][nt * 16 + lr] = acc[nt][j];
  }
  __syncthreads();
  if (kh == 0) {
#pragma unroll
    for (int nt = 0; nt < 4; ++nt) {
      const int n = nt * 16 + lr;
      const float bb = bo[n];
#pragma unroll
      for (int j = 0; j < 4; ++j) {
        const int m = m0 + lg * 4 + j;
        float vv = acc[nt][j] + red[wm][lg * 4 + j][n] + bb;
        out[(size_t)m * 64 + n] = vv > 0.f ? vv : 0.f;
      }
    }
  }
}

// ---------------------------------------------------------------------------
extern "C" void kernel_launch(void* const* d_in, const int* in_sizes, int n_in,
                              void* d_out, int out_size, void* d_ws, size_t ws_size,
                              hipStream_t stream) {
  const float* x  = (const float*)d_in[0];
  const float* Wq = (const float*)d_in[1];
  const float* bq = (const float*)d_in[2];
  const float* Wk = (const float*)d_in[3];
  const float* bk = (const float*)d_in[4];
  const float* Wv = (const float*)d_in[5];
  const float* bv = (const float*)d_in[6];
  const float* Wo = (const float*)d_in[7];
  const float* bo = (const float*)d_in[8];
  float* out = (float*)d_out;            // z_out: 8*1024*64 = 524288 f32
  float* att = out + 524288;             // att:   8*16*1024*1024 f32

  // workspace layout (~92 MB)
  char* ws = (char*)d_ws;
  size_t off = 0;
  ushort* xb  = (ushort*)(ws + off); off += (size_t)8192 * 1024 * 2;
  ushort* Wp  = (ushort*)(ws + off); off += (size_t)3072 * 1024 * 2;
  ushort* Wop = (ushort*)(ws + off); off += (size_t)64 * 1024 * 2;
  float* bqkv = (float*)(ws + off);  off += (size_t)3072 * 4;
  ushort* q   = (ushort*)(ws + off); off += (size_t)128 * 1024 * 64 * 2;
  ushort* k   = (ushort*)(ws + off); off += (size_t)128 * 1024 * 64 * 2;
  ushort* vT  = (ushort*)(ws + off); off += (size_t)128 * 64 * 1024 * 2;
  ushort* hds = (ushort*)(ws + off); off += (size_t)8192 * 1024 * 2;
  (void)ws_size; (void)in_sizes; (void)n_in; (void)out_size;

  pack_x<<<dim3(8192), dim3(256), 0, stream>>>(x, xb);
  pack_w<<<dim3(12288), dim3(256), 0, stream>>>(Wq, Wk, Wv, Wp);
  pack_misc<<<dim3(269), dim3(256), 0, stream>>>(Wo, bq, bk, bv, Wop, bqkv);
  gemm_qkv<<<dim3(1536), dim3(256), 0, stream>>>(xb, Wp, bqkv, q, k, vT);
  attn_kernel<<<dim3(2048), dim3(256), 0, stream>>>(q, k, vT, att, hds);
  gemm_out<<<dim3(256), dim3(256), 0, stream>>>(hds, Wop, bo, out);
}

// Round 12
// 229.051 us; speedup vs baseline: 2.5360x; 1.2163x over previous
//
#include <hip/hip_runtime.h>

// ---------------------------------------------------------------------------
// AttentionMultiHead: x[8,1024,1024] f32, per-head Wq/Wk/Wv[16,1024,64]+bias,
// Wo[1024,64]+bo. Outputs: z_out[8,1024,64] f32, att[8,16,1024,1024] f32 (raw).
//
// Ledger after R11 (278.6us): attn ~163us (floor ~93), gemm_qkv ~55, packs+gaps
// ~45, out ~8. R11 (-70us) confirmed VMEM request-rate as attn's limiter by
// coalescing the LOAD side (K/V staged to LDS via global_load_lds).
// R12: the att STORE side still writes 16 scattered 64B segments/instr
// (16 q-rows x 4KB stride; 8.4M line-touches ~ 3.2 req/cy/XCD). Stage scores
// in per-wave LDS (32-kv slices interleaved with PV) and flush as fully-
// covered 128B-aligned line writes (8 rows x 128B per instr): line-touches/KB
// 16 -> 8, all lines full (no partial-line HBM cost). Bit-identical values.
// Also: 3 pack kernels fused into one (fewer launch gaps, concurrent).
// ---------------------------------------------------------------------------

typedef __bf16 bf16x8 __attribute__((ext_vector_type(8)));
typedef float f32x4 __attribute__((ext_vector_type(4)));
typedef unsigned short u16x8 __attribute__((ext_vector_type(8)));
typedef unsigned short u16x4 __attribute__((ext_vector_type(4)));

typedef __attribute__((address_space(1))) unsigned int as1_u32;
typedef __attribute__((address_space(3))) unsigned int as3_u32;

#define MFMA16(a, b, c) __builtin_amdgcn_mfma_f32_16x16x32_bf16(a, b, c, 0, 0, 0)

__device__ __forceinline__ void gload_lds16(const void* g, void* l) {
  __builtin_amdgcn_global_load_lds((const as1_u32*)g, (as3_u32*)l, 16, 0, 0);
}

__device__ __forceinline__ unsigned short f2bf(float f) {
  union { float f; unsigned u; } a; a.f = f;
  unsigned r = a.u + 0x7FFFu + ((a.u >> 16) & 1u);  // RNE
  return (unsigned short)(r >> 16);
}

// ---------------- fused pack kernel ----------------
// blocks [0,8192): x->bf16; [8192,20480): Wq|Wk|Wv -> Wp[3072][1024] B^T
// (XCD-swizzled); [20480,20749): Wop + bqkv.
__global__ __launch_bounds__(256) void pack_all(const float* __restrict__ x, const float* __restrict__ Wq,
                                                const float* __restrict__ Wk, const float* __restrict__ Wv,
                                                const float* __restrict__ Wo, const float* __restrict__ bq,
                                                const float* __restrict__ bk, const float* __restrict__ bv,
                                                ushort* __restrict__ xb, ushort* __restrict__ Wp,
                                                ushort* __restrict__ Wop, float* __restrict__ bqkv) {
  const int bid = blockIdx.x;
  if (bid < 8192) {
    const size_t i = ((size_t)bid * 256 + threadIdx.x) * 4;
    const float4 v = *(const float4*)(x + i);
    u16x4 o; o[0] = f2bf(v.x); o[1] = f2bf(v.y); o[2] = f2bf(v.z); o[3] = f2bf(v.w);
    *(u16x4*)(xb + i) = o;
  } else if (bid < 20480) {
    const int b2 = bid - 8192;
    const int swz = (b2 & 7) * 1536 + (b2 >> 3);
    const int o = swz * 256 + threadIdx.x;  // 0 .. 3072*1024
    const int n = o >> 10, d = o & 1023;
    const int proj = n >> 10, hk = n & 1023;
    const float* W = proj == 0 ? Wq : (proj == 1 ? Wk : Wv);
    const int h = hk >> 6, kk = hk & 63;
    Wp[o] = f2bf(W[((size_t)h * 1024 + d) * 64 + kk]);
  } else {
    const int idx = (bid - 20480) * 256 + threadIdx.x;
    if (idx < 65536) {
      const int n = idx >> 10, c = idx & 1023;   // Wop[n][c] = Wo[c][n]
      Wop[idx] = f2bf(Wo[c * 64 + n]);
    } else if (idx < 65536 + 3072) {
      const int n = idx - 65536;
      const int proj = n >> 10;
      const float* bb = proj == 0 ? bq : (proj == 1 ? bk : bv);
      bqkv[n] = bb[n & 1023];
    }
  }
}

// ---------------- QKV projection GEMM (R3 structure) ----------------
__global__ __launch_bounds__(256) void gemm_qkv(const ushort* __restrict__ xb, const ushort* __restrict__ Wp,
                                                const float* __restrict__ bqkv, ushort* __restrict__ qo,
                                                ushort* __restrict__ ko, ushort* __restrict__ vTo) {
  __shared__ ushort As[128 * 32], Bs[128 * 32];
  const int bid = blockIdx.x;                 // 1536 blocks
  const int swz = (bid & 7) * 192 + (bid >> 3);
  const int by = swz / 24, bx = swz - by * 24;
  const int t = threadIdx.x, w = t >> 6, l = t & 63, lg = l >> 4, lr = l & 15;
  const int m0 = by * 128, n0 = bx * 128;
  const int wm = w >> 1, wn = w & 1;
  const int srow = l >> 2, sslot = l & 3;
  f32x4 acc[4][4] = {};
  for (int kt = 0; kt < 32; ++kt) {
    __syncthreads();
#pragma unroll
    for (int c = 0; c < 2; ++c) {
      const int cc = w * 2 + c;              // 0..7, 1KB chunk per wave-call
      const int row = cc * 16 + srow;        // LDS linear == row*64B + slot*16B
      gload_lds16(xb + (size_t)(m0 + row) * 1024 + kt * 32 + sslot * 8, &As[cc * 512]);
      gload_lds16(Wp + (size_t)(n0 + row) * 1024 + kt * 32 + sslot * 8, &Bs[cc * 512]);
    }
    __syncthreads();
    bf16x8 af[4], bfr[4];
#pragma unroll
    for (int mt = 0; mt < 4; ++mt)
      af[mt] = *(const bf16x8*)(&As[(wm * 64 + mt * 16 + lr) * 32 + lg * 8]);
#pragma unroll
    for (int nt = 0; nt < 4; ++nt)
      bfr[nt] = *(const bf16x8*)(&Bs[(wn * 64 + nt * 16 + lr) * 32 + lg * 8]);
#pragma unroll
    for (int mt = 0; mt < 4; ++mt)
#pragma unroll
      for (int nt = 0; nt < 4; ++nt)
        acc[mt][nt] = MFMA16(af[mt], bfr[nt], acc[mt][nt]);
  }
  // epilogue: bias + relu -> bf16. proj uniform across the wave (16-aligned n-chunks).
#pragma unroll
  for (int nt = 0; nt < 4; ++nt) {
    const int n = n0 + wn * 64 + nt * 16 + lr;
    const float bias = bqkv[n];
    const int proj = n >> 10, h = (n >> 6) & 15, dk = n & 63;
#pragma unroll
    for (int mt = 0; mt < 4; ++mt) {
      const int mb = m0 + wm * 64 + mt * 16 + lg * 4;  // j-quad base, same b & 4-aligned s
      const int b = mb >> 10, s = mb & 1023;
      float vv[4];
#pragma unroll
      for (int j = 0; j < 4; ++j) {
        float a = acc[mt][nt][j] + bias;
        vv[j] = a > 0.f ? a : 0.f;
      }
      if (proj == 2) {
        u16x4 o; o[0] = f2bf(vv[0]); o[1] = f2bf(vv[1]); o[2] = f2bf(vv[2]); o[3] = f2bf(vv[3]);
        *(u16x4*)(vTo + ((size_t)(b * 16 + h) * 64 + dk) * 1024 + s) = o;
      } else {
        ushort* op = proj == 0 ? qo : ko;
#pragma unroll
        for (int j = 0; j < 4; ++j)
          op[((size_t)(b * 16 + h) * 1024 + s + j) * 64 + dk] = f2bf(vv[j]);
      }
    }
  }
}

// ---------------- fused attention (LDS K/V + LDS-staged 128B-line att flush) -
// 2048 blocks (XCD-swizzled); 4 waves x 16 q-rows (lane lr = q-row).
// Per 128-kv group: stage K,V to LDS (coalesced gload_lds, chunk-XOR source
// pre-swizzle); QK^T (swapped) for all 8 frags; then 4 s-slices of 32 kv:
// {exp->p_q quarter + scores->s_st quarter; lgkmcnt; flush s_st as 8-row x
// 128B fully-covered nt line-writes; PV 4 MFMA (retire shadow)}. All values
// bit-identical to R11; only the att store geometry changes.
__global__ __launch_bounds__(256) void attn_kernel(const ushort* __restrict__ qg, const ushort* __restrict__ kg,
                                                   const ushort* __restrict__ vT, float* __restrict__ att,
                                                   ushort* __restrict__ heads) {
  const int bid = blockIdx.x;                 // 2048
  const int swz = (bid & 7) * 256 + (bid >> 3);
  const int qt = swz & 15, bh = swz >> 4;
  const int t = threadIdx.x, w = t >> 6, l = t & 63;
  const int lg = l >> 4, lr = l & 15;
  __shared__ ushort Ks[128 * 64];         // 16 KB, chunk-swizzled rows
  __shared__ ushort Vs[64 * 128];         // 16 KB, chunk-swizzled rows
  __shared__ ushort p_q[4][16][40];       // 5 KB, P quarter (32 kv), reused per slice
  __shared__ float s_st[4][16][40];       // 10 KB, score quarter (32 kv), reused

  const ushort* qb = qg + (size_t)bh * 65536;
  const ushort* kb = kg + (size_t)bh * 65536;
  const ushort* vb = vT + (size_t)bh * 65536;
  const int qrow0 = qt * 64 + w * 16;

  const bf16x8 qf0 = *(const bf16x8*)(qb + (qrow0 + lr) * 64 + lg * 8);
  const bf16x8 qf1 = *(const bf16x8*)(qb + (qrow0 + lr) * 64 + 32 + lg * 8);

  // staging lane geometry (per 1KB call)
  const int krow = l >> 3, kch = l & 7;    // K: 8 rows x 8 chunks(16B)
  const int vrow = l >> 4, vch = l & 15;   // V: 4 rows x 16 chunks(16B)
  const int frow = l >> 3, fcol = (l & 7) * 4;  // flush: 8 rows x 128B per instr

  const float C2 = 0.125f * 1.44269504f;   // 1/sqrt(64) in exp2 domain
  f32x4 oacc[4] = {};
  float lsum = 0.f;
  float* attw = att + ((size_t)bh * 1024 + qrow0) * 1024;

  for (int g = 0; g < 8; ++g) {
    const int kv0 = g * 128;
    __syncthreads();   // all waves done reading previous group's tiles
#pragma unroll
    for (int c2 = 0; c2 < 4; ++c2) {
      const int call = w * 4 + c2;
      const int r = call * 8 + krow;       // K local row 0..127
      gload_lds16(kb + (size_t)(kv0 + r) * 64 + ((kch ^ (r & 7)) * 8), &Ks[call * 512]);
      const int rv = call * 4 + vrow;      // V local row (dk) 0..63
      gload_lds16(vb + (size_t)rv * 1024 + kv0 + ((vch ^ (rv & 15)) * 8), &Vs[call * 512]);
    }
    __syncthreads();   // stage complete
    // QK^T from LDS: sf[f][j] = S[q=lr][kv = kv0 + f*16 + lg*4 + j]
    f32x4 sf[8];
#pragma unroll
    for (int f = 0; f < 8; ++f) {
      const int r = f * 16 + lr;
      const bf16x8 kf0 = *(const bf16x8*)(&Ks[r * 64 + ((lg ^ (r & 7)) * 8)]);
      const bf16x8 kf1 = *(const bf16x8*)(&Ks[r * 64 + (((4 + lg) ^ (r & 7)) * 8)]);
      f32x4 s = {};
      s = MFMA16(kf0, qf0, s);
      s = MFMA16(kf1, qf1, s);
      sf[f] = s;
    }
    // 4 slices of 32 kv: exp/pack + score-stage -> flush (128B lines) + PV
#pragma unroll
    for (int s = 0; s < 4; ++s) {
#pragma unroll
      for (int fi = 0; fi < 2; ++fi) {
        const int f = 2 * s + fi;
        u16x4 pk;
#pragma unroll
        for (int j = 0; j < 4; ++j) {
          const float p = exp2f(sf[f][j] * C2);
          lsum += p;
          pk[j] = f2bf(p);
        }
        *(u16x4*)(&p_q[w][lr][fi * 16 + lg * 4]) = pk;
        *(f32x4*)(&s_st[w][lr][fi * 16 + lg * 4]) = sf[f];
      }
      // per-wave LDS region; DS ops wave-program-order; wait for writes
      asm volatile("s_waitcnt lgkmcnt(0)" ::: "memory");
      __builtin_amdgcn_sched_barrier(0);
      const bf16x8 pa = *(const bf16x8*)(&p_q[w][lr][lg * 8]);
      // flush this slice: 2 instrs x 8 rows x 128B fully-covered aligned lines
#pragma unroll
      for (int i = 0; i < 2; ++i) {
        const int r = i * 8 + frow;
        const f32x4 fv = *(const f32x4*)(&s_st[w][r][fcol]);
        __builtin_nontemporal_store(fv,
            (f32x4*)(attw + (size_t)r * 1024 + kv0 + s * 32 + fcol));
      }
      // PV for this slice (LDS/reg only -> store retire shadow)
#pragma unroll
      for (int nt = 0; nt < 4; ++nt) {
        const int r = nt * 16 + lr;
        const bf16x8 vf = *(const bf16x8*)(&Vs[r * 128 + (((s * 4 + lg) ^ lr) * 8)]);
        oacc[nt] = MFMA16(pa, vf, oacc[nt]);
      }
    }
  }
  // row sums: reduce lane partials across lg groups
  lsum += __shfl_xor(lsum, 16, 64);
  lsum += __shfl_xor(lsum, 32, 64);
  float rdiv[4];
#pragma unroll
  for (int j = 0; j < 4; ++j) rdiv[j] = 1.f / __shfl(lsum, lg * 4 + j, 16);
  const int b = bh >> 4, h = bh & 15;
#pragma unroll
  for (int nt = 0; nt < 4; ++nt)
#pragma unroll
    for (int j = 0; j < 4; ++j)
      __builtin_nontemporal_store(f2bf(oacc[nt][j] * rdiv[j]),
          heads + (size_t)(b * 1024 + qrow0 + lg * 4 + j) * 1024 + h * 64 + nt * 16 + lr);
}

// ---------------- output GEMM: z_out = relu(heads @ Wo + bo) ----------------
__global__ __launch_bounds__(256) void gemm_out(const ushort* __restrict__ z, const ushort* __restrict__ Wop,
                                                const float* __restrict__ bo, float* __restrict__ out) {
  __shared__ float red[2][16][64];
  const int t = threadIdx.x, w = t >> 6, l = t & 63, lg = l >> 4, lr = l & 15;
  const int wm = w & 1, kh = w >> 1;
  const int m0 = blockIdx.x * 32 + wm * 16;
  f32x4 acc[4] = {};
  for (int kk = kh * 16; kk < kh * 16 + 16; ++kk) {
    bf16x8 af = *(const bf16x8*)(z + (size_t)(m0 + lr) * 1024 + kk * 32 + lg * 8);
#pragma unroll
    for (int nt = 0; nt < 4; ++nt) {
      bf16x8 bfr = *(const bf16x8*)(Wop + (size_t)(nt * 16 + lr) * 1024 + kk * 32 + lg * 8);
      acc[nt] = MFMA16(af, bfr, acc[nt]);
    }
  }
  if (kh == 1) {
#pragma unroll
    for (int nt = 0; nt < 4; ++nt)
#pragma unroll
      for (int j = 0; j < 4; ++j) red[wm][lg * 4 + j][nt * 16 + lr] = acc[nt][j];
  }
  __syncthreads();
  if (kh == 0) {
#pragma unroll
    for (int nt = 0; nt < 4; ++nt) {
      const int n = nt * 16 + lr;
      const float bb = bo[n];
#pragma unroll
      for (int j = 0; j < 4; ++j) {
        const int m = m0 + lg * 4 + j;
        float vv = acc[nt][j] + red[wm][lg * 4 + j][n] + bb;
        out[(size_t)m * 64 + n] = vv > 0.f ? vv : 0.f;
      }
    }
  }
}

// ---------------------------------------------------------------------------
extern "C" void kernel_launch(void* const* d_in, const int* in_sizes, int n_in,
                              void* d_out, int out_size, void* d_ws, size_t ws_size,
                              hipStream_t stream) {
  const float* x  = (const float*)d_in[0];
  const float* Wq = (const float*)d_in[1];
  const float* bq = (const float*)d_in[2];
  const float* Wk = (const float*)d_in[3];
  const float* bk = (const float*)d_in[4];
  const float* Wv = (const float*)d_in[5];
  const float* bv = (const float*)d_in[6];
  const float* Wo = (const float*)d_in[7];
  const float* bo = (const float*)d_in[8];
  float* out = (float*)d_out;            // z_out: 8*1024*64 = 524288 f32
  float* att = out + 524288;             // att:   8*16*1024*1024 f32

  // workspace layout (~92 MB)
  char* ws = (char*)d_ws;
  size_t off = 0;
  ushort* xb  = (ushort*)(ws + off); off += (size_t)8192 * 1024 * 2;
  ushort* Wp  = (ushort*)(ws + off); off += (size_t)3072 * 1024 * 2;
  ushort* Wop = (ushort*)(ws + off); off += (size_t)64 * 1024 * 2;
  float* bqkv = (float*)(ws + off);  off += (size_t)3072 * 4;
  ushort* q   = (ushort*)(ws + off); off += (size_t)128 * 1024 * 64 * 2;
  ushort* k   = (ushort*)(ws + off); off += (size_t)128 * 1024 * 64 * 2;
  ushort* vT  = (ushort*)(ws + off); off += (size_t)128 * 64 * 1024 * 2;
  ushort* hds = (ushort*)(ws + off); off += (size_t)8192 * 1024 * 2;
  (void)ws_size; (void)in_sizes; (void)n_in; (void)out_size;

  pack_all<<<dim3(20749), dim3(256), 0, stream>>>(x, Wq, Wk, Wv, Wo, bq, bk, bv,
                                                  xb, Wp, Wop, bqkv);
  gemm_qkv<<<dim3(1536), dim3(256), 0, stream>>>(xb, Wp, bqkv, q, k, vT);
  attn_kernel<<<dim3(2048), dim3(256), 0, stream>>>(q, k, vT, att, hds);
  gemm_out<<<dim3(256), dim3(256), 0, stream>>>(hds, Wop, bo, out);
}